// Round 1
// baseline (685.639 us; speedup 1.0000x reference)
//
#include <hip/hip_runtime.h>
#include <math.h>

#define N_NODES 100000
#define N_EDGES 1000000
#define D_MODEL 128
#define EDGE_DIM 64
#define SCHUNK 250
#define NSB 400

typedef short bf16x8 __attribute__((ext_vector_type(8)));
typedef float f32x4 __attribute__((ext_vector_type(4)));

__device__ __forceinline__ short f2bf(float f) {
    union { float f; unsigned u; } v; v.f = f;
    unsigned r = v.u + 0x7FFFu + ((v.u >> 16) & 1u);
    return (short)(r >> 16);
}
__device__ __forceinline__ float gelu_exact(float x) {
    return 0.5f * x * (1.0f + erff(x * 0.70710678118654752f));
}

// ---------------- y_src = x_src@W_src (bf16 out), z = x_dst@W_dst + b_dst (f32 out)
__global__ __launch_bounds__(256) void k_node_linear(
    const float* __restrict__ x_src, const float* __restrict__ x_dst,
    const float* __restrict__ W_src, const float* __restrict__ W_dst,
    const float* __restrict__ b_dst,
    short* __restrict__ ysrc, float* __restrict__ z)
{
    __shared__ __align__(16) short Bf[4][8][64][8];  // 32 KB: B fragments, bf16
    const int tid = threadIdx.x;
    const int lane = tid & 63;
    const int wid = tid >> 6;
    const int l15 = lane & 15;
    const int lg = lane >> 4;
    const int row0 = blockIdx.x * 128 + wid * 32;

    for (int mat = 0; mat < 2; ++mat) {
        const float* __restrict__ W = mat ? W_dst : W_src;
        const float* __restrict__ X = mat ? x_dst : x_src;
        __syncthreads();
        for (int idx = tid; idx < 4 * 8 * 64; idx += 256) {
            int ls = idx & 63;
            int nt = (idx >> 6) & 7;
            int kb = idx >> 9;
            int col = nt * 16 + (ls & 15);
            int kbase = kb * 32 + (ls >> 4) * 8;
            short* d8 = &Bf[kb][nt][ls][0];
            #pragma unroll
            for (int e = 0; e < 8; ++e) d8[e] = f2bf(W[(kbase + e) * D_MODEL + col]);
        }
        __syncthreads();

        f32x4 acc[2][8];
        #pragma unroll
        for (int st = 0; st < 2; ++st)
            #pragma unroll
            for (int nt = 0; nt < 8; ++nt) {
                f32x4 zz = {0.f, 0.f, 0.f, 0.f};
                acc[st][nt] = zz;
            }

        #pragma unroll
        for (int kb = 0; kb < 4; ++kb) {
            bf16x8 a[2];
            #pragma unroll
            for (int st = 0; st < 2; ++st) {
                int r = row0 + st * 16 + l15;
                bf16x8 t = {0, 0, 0, 0, 0, 0, 0, 0};
                if (r < N_NODES) {
                    const float* p = X + r * D_MODEL + kb * 32 + lg * 8;
                    float4 v0 = *reinterpret_cast<const float4*>(p);
                    float4 v1 = *reinterpret_cast<const float4*>(p + 4);
                    t[0] = f2bf(v0.x); t[1] = f2bf(v0.y); t[2] = f2bf(v0.z); t[3] = f2bf(v0.w);
                    t[4] = f2bf(v1.x); t[5] = f2bf(v1.y); t[6] = f2bf(v1.z); t[7] = f2bf(v1.w);
                }
                a[st] = t;
            }
            #pragma unroll
            for (int nt = 0; nt < 8; ++nt) {
                bf16x8 b = *reinterpret_cast<const bf16x8*>(&Bf[kb][nt][lane][0]);
                acc[0][nt] = __builtin_amdgcn_mfma_f32_16x16x32_bf16(a[0], b, acc[0][nt], 0, 0, 0);
                acc[1][nt] = __builtin_amdgcn_mfma_f32_16x16x32_bf16(a[1], b, acc[1][nt], 0, 0, 0);
            }
        }

        #pragma unroll
        for (int st = 0; st < 2; ++st) {
            int rowb = row0 + st * 16 + lg * 4;
            #pragma unroll
            for (int nt = 0; nt < 8; ++nt) {
                int col = nt * 16 + l15;
                float bias = mat ? b_dst[col] : 0.0f;
                #pragma unroll
                for (int r = 0; r < 4; ++r) {
                    int row = rowb + r;
                    if (row < N_NODES) {
                        float v = acc[st][nt][r];
                        if (mat) z[row * D_MODEL + col] = v + bias;
                        else     ysrc[row * D_MODEL + col] = f2bf(v);
                    }
                }
            }
        }
    }
}

// ---------------- gate[e] = sigmoid(gelu(ea@Wg1+bg1)@Wg2+bg2)
__global__ __launch_bounds__(256) void k_gate(
    const float* __restrict__ ea, const float* __restrict__ Wg1,
    const float* __restrict__ bg1, const float* __restrict__ Wg2,
    const float* __restrict__ bg2, float* __restrict__ gate)
{
    __shared__ __align__(16) short Bf[2][8][64][8];  // 16 KB
    const int tid = threadIdx.x;
    const int lane = tid & 63;
    const int wid = tid >> 6;
    const int l15 = lane & 15;
    const int lg = lane >> 4;

    for (int idx = tid; idx < 2 * 8 * 64; idx += 256) {
        int ls = idx & 63;
        int nt = (idx >> 6) & 7;
        int kb = idx >> 9;
        int col = nt * 16 + (ls & 15);
        int kbase = kb * 32 + (ls >> 4) * 8;
        short* d8 = &Bf[kb][nt][ls][0];
        #pragma unroll
        for (int e = 0; e < 8; ++e) d8[e] = f2bf(Wg1[(kbase + e) * D_MODEL + col]);
    }
    __syncthreads();

    const int e0 = blockIdx.x * 128 + wid * 32;
    f32x4 acc[2][8];
    #pragma unroll
    for (int st = 0; st < 2; ++st)
        #pragma unroll
        for (int nt = 0; nt < 8; ++nt) {
            f32x4 zz = {0.f, 0.f, 0.f, 0.f};
            acc[st][nt] = zz;
        }

    #pragma unroll
    for (int kb = 0; kb < 2; ++kb) {
        bf16x8 a[2];
        #pragma unroll
        for (int st = 0; st < 2; ++st) {
            int r = e0 + st * 16 + l15;
            bf16x8 t = {0, 0, 0, 0, 0, 0, 0, 0};
            if (r < N_EDGES) {
                const float* p = ea + r * EDGE_DIM + kb * 32 + lg * 8;
                float4 v0 = *reinterpret_cast<const float4*>(p);
                float4 v1 = *reinterpret_cast<const float4*>(p + 4);
                t[0] = f2bf(v0.x); t[1] = f2bf(v0.y); t[2] = f2bf(v0.z); t[3] = f2bf(v0.w);
                t[4] = f2bf(v1.x); t[5] = f2bf(v1.y); t[6] = f2bf(v1.z); t[7] = f2bf(v1.w);
            }
            a[st] = t;
        }
        #pragma unroll
        for (int nt = 0; nt < 8; ++nt) {
            bf16x8 b = *reinterpret_cast<const bf16x8*>(&Bf[kb][nt][lane][0]);
            acc[0][nt] = __builtin_amdgcn_mfma_f32_16x16x32_bf16(a[0], b, acc[0][nt], 0, 0, 0);
            acc[1][nt] = __builtin_amdgcn_mfma_f32_16x16x32_bf16(a[1], b, acc[1][nt], 0, 0, 0);
        }
    }

    float part[2][4] = {{0.f, 0.f, 0.f, 0.f}, {0.f, 0.f, 0.f, 0.f}};
    #pragma unroll
    for (int nt = 0; nt < 8; ++nt) {
        int col = nt * 16 + l15;
        float b1 = bg1[col];
        float w2 = Wg2[col];
        #pragma unroll
        for (int st = 0; st < 2; ++st)
            #pragma unroll
            for (int r = 0; r < 4; ++r) {
                float h = acc[st][nt][r] + b1;
                part[st][r] += gelu_exact(h) * w2;
            }
    }
    #pragma unroll
    for (int m = 1; m <= 8; m <<= 1)
        #pragma unroll
        for (int st = 0; st < 2; ++st)
            #pragma unroll
            for (int r = 0; r < 4; ++r)
                part[st][r] += __shfl_xor(part[st][r], m);

    float b2 = bg2[0];
    if (l15 == 0) {
        #pragma unroll
        for (int st = 0; st < 2; ++st)
            #pragma unroll
            for (int r = 0; r < 4; ++r) {
                int e = e0 + st * 16 + lg * 4 + r;
                if (e < N_EDGES) gate[e] = 1.0f / (1.0f + expf(-(part[st][r] + b2)));
            }
    }
}

// ---------------- CSR build
__global__ void k_zero_int(int* __restrict__ p, int n) {
    int i = blockIdx.x * 256 + threadIdx.x;
    if (i < n) p[i] = 0;
}
__global__ void k_deg(const int* __restrict__ dst, int* __restrict__ deg) {
    int e = blockIdx.x * 256 + threadIdx.x;
    if (e < N_EDGES) atomicAdd(&deg[dst[e]], 1);
}
__global__ __launch_bounds__(256) void k_scan1(const int* __restrict__ deg, int* __restrict__ bsum) {
    __shared__ int s[256];
    int tid = threadIdx.x;
    int i = blockIdx.x * SCHUNK + tid;
    int v = (tid < SCHUNK && i < N_NODES) ? deg[i] : 0;
    s[tid] = v; __syncthreads();
    for (int off = 128; off > 0; off >>= 1) {
        if (tid < off) s[tid] += s[tid + off];
        __syncthreads();
    }
    if (tid == 0) bsum[blockIdx.x] = s[0];
}
__global__ __launch_bounds__(512) void k_scan2(const int* __restrict__ bsum, int* __restrict__ boff) {
    __shared__ int s[512];
    int tid = threadIdx.x;
    int v = (tid < NSB) ? bsum[tid] : 0;
    s[tid] = v; __syncthreads();
    for (int off = 1; off < 512; off <<= 1) {
        int t = (tid >= off) ? s[tid - off] : 0;
        __syncthreads();
        s[tid] += t;
        __syncthreads();
    }
    if (tid < NSB) boff[tid] = s[tid] - v;
}
__global__ __launch_bounds__(256) void k_scan3(const int* __restrict__ deg, const int* __restrict__ boff,
                                               int* __restrict__ row_start, int* __restrict__ cursor) {
    __shared__ int s[256];
    int tid = threadIdx.x;
    int i = blockIdx.x * SCHUNK + tid;
    int v = (tid < SCHUNK && i < N_NODES) ? deg[i] : 0;
    s[tid] = v; __syncthreads();
    for (int off = 1; off < 256; off <<= 1) {
        int t = (tid >= off) ? s[tid - off] : 0;
        __syncthreads();
        s[tid] += t;
        __syncthreads();
    }
    int excl = s[tid] - v;
    if (tid < SCHUNK && i < N_NODES) {
        int rs = boff[blockIdx.x] + excl;
        row_start[i] = rs;
        cursor[i] = rs;
    }
}
__global__ void k_fill(const int* __restrict__ dst, int* __restrict__ cursor, int* __restrict__ eid) {
    int e = blockIdx.x * 256 + threadIdx.x;
    if (e < N_EDGES) {
        int d = dst[e];
        int p = atomicAdd(&cursor[d], 1);
        eid[p] = e;
    }
}

// ---------------- per-node gather + mean + residual + LN + GELU (one wave per node)
__global__ __launch_bounds__(256) void k_agg(
    const int* __restrict__ eid, const int* __restrict__ src,
    const float* __restrict__ gate, const int* __restrict__ row_start,
    const int* __restrict__ deg, const short* __restrict__ ysrc,
    const float* __restrict__ z, const float* __restrict__ gamma,
    const float* __restrict__ beta, float* __restrict__ out)
{
    const int lane = threadIdx.x & 63;
    const int wid = threadIdx.x >> 6;
    const int n = blockIdx.x * 4 + wid;
    const int start = row_start[n];
    const int dg = deg[n];
    const int c0 = lane * 2;

    float a0 = 0.f, a1 = 0.f;
    for (int base = 0; base < dg; base += 64) {
        int j = base + lane;
        int sN = 0; float gv = 0.f;
        if (j < dg) {
            int e = eid[start + j];
            sN = src[e];
            gv = gate[e];
        }
        int cnt = min(dg - base, 64);
        for (int t = 0; t < cnt; ++t) {
            int s = __shfl(sN, t);
            float g = __shfl(gv, t);
            unsigned pv = *reinterpret_cast<const unsigned*>(&ysrc[s * D_MODEL + c0]);
            a0 += g * __uint_as_float((pv & 0xFFFFu) << 16);
            a1 += g * __uint_as_float(pv & 0xFFFF0000u);
        }
    }

    float inv = 1.0f / fmaxf((float)dg, 1.0f);
    float t0 = a0 * inv + z[n * D_MODEL + c0];
    float t1 = a1 * inv + z[n * D_MODEL + c0 + 1];

    float sum = t0 + t1;
    #pragma unroll
    for (int m = 1; m <= 32; m <<= 1) sum += __shfl_xor(sum, m);
    float mu = sum * (1.0f / 128.0f);
    float d0 = t0 - mu, d1 = t1 - mu;
    float vs = d0 * d0 + d1 * d1;
    #pragma unroll
    for (int m = 1; m <= 32; m <<= 1) vs += __shfl_xor(vs, m);
    float rstd = rsqrtf(vs * (1.0f / 128.0f) + 1e-5f);

    float o0 = d0 * rstd * gamma[c0] + beta[c0];
    float o1 = d1 * rstd * gamma[c0 + 1] + beta[c0 + 1];
    float2 o = make_float2(gelu_exact(o0), gelu_exact(o1));
    *reinterpret_cast<float2*>(&out[n * D_MODEL + c0]) = o;
}

extern "C" void kernel_launch(void* const* d_in, const int* in_sizes, int n_in,
                              void* d_out, int out_size, void* d_ws, size_t ws_size,
                              hipStream_t stream)
{
    const float* x_src = (const float*)d_in[0];
    const float* x_dst = (const float*)d_in[1];
    const float* ea    = (const float*)d_in[2];
    const int*   ei    = (const int*)d_in[3];
    const float* W_src = (const float*)d_in[4];
    const float* W_dst = (const float*)d_in[5];
    const float* b_dst = (const float*)d_in[6];
    const float* Wg1   = (const float*)d_in[7];
    const float* bg1   = (const float*)d_in[8];
    const float* Wg2   = (const float*)d_in[9];
    const float* bg2   = (const float*)d_in[10];
    const float* gamma = (const float*)d_in[11];
    const float* beta  = (const float*)d_in[12];
    const int* srcIdx = ei;
    const int* dstIdx = ei + N_EDGES;

    char* ws = (char*)d_ws;
    short* ysrc   = (short*)(ws);                  // 25,600,000 B (bf16 y_src)
    float* z      = (float*)(ws + 25600000);       // 51,200,000 B
    float* gate   = (float*)(ws + 76800000);       //  4,000,000 B
    int*   deg    = (int*)(ws + 80800000);         //    400,000 B
    int*   rstart = (int*)(ws + 81200000);         //    400,000 B
    int*   cursor = (int*)(ws + 81600000);         //    400,000 B
    int*   eid    = (int*)(ws + 82000000);         //  4,000,000 B
    int*   bsum   = (int*)(ws + 86000000);         //      1,600 B
    int*   boff   = (int*)(ws + 86003200);         //      1,600 B

    float* out = (float*)d_out;

    hipLaunchKernelGGL(k_zero_int, dim3((N_NODES + 255) / 256), dim3(256), 0, stream, deg, N_NODES);
    hipLaunchKernelGGL(k_node_linear, dim3(782), dim3(256), 0, stream,
                       x_src, x_dst, W_src, W_dst, b_dst, ysrc, z);
    hipLaunchKernelGGL(k_gate, dim3(7813), dim3(256), 0, stream,
                       ea, Wg1, bg1, Wg2, bg2, gate);
    hipLaunchKernelGGL(k_deg, dim3((N_EDGES + 255) / 256), dim3(256), 0, stream, dstIdx, deg);
    hipLaunchKernelGGL(k_scan1, dim3(NSB), dim3(256), 0, stream, deg, bsum);
    hipLaunchKernelGGL(k_scan2, dim3(1), dim3(512), 0, stream, bsum, boff);
    hipLaunchKernelGGL(k_scan3, dim3(NSB), dim3(256), 0, stream, deg, boff, rstart, cursor);
    hipLaunchKernelGGL(k_fill, dim3((N_EDGES + 255) / 256), dim3(256), 0, stream, dstIdx, cursor, eid);
    hipLaunchKernelGGL(k_agg, dim3(N_NODES / 4), dim3(256), 0, stream,
                       eid, srcIdx, gate, rstart, deg, ysrc, z, gamma, beta, out);
}

// Round 3
// 309.578 us; speedup vs baseline: 2.2148x; 2.2148x over previous
//
#include <hip/hip_runtime.h>
#include <hip/hip_fp16.h>
#include <math.h>

#define N_NODES 100000
#define N_EDGES 1000000
#define D_MODEL 128
#define EDGE_DIM 64
#define SCHUNK 250
#define NSB 400

typedef short bf16x8 __attribute__((ext_vector_type(8)));
typedef float f32x4 __attribute__((ext_vector_type(4)));

__device__ __forceinline__ short f2bf(float f) {
    union { float f; unsigned u; } v; v.f = f;
    unsigned r = v.u + 0x7FFFu + ((v.u >> 16) & 1u);
    return (short)(r >> 16);
}
// tanh-form GELU: x*sigmoid(2t), t = 0.79788456(x + 0.044715 x^3). Max abs dev ~4e-4.
__device__ __forceinline__ float gelu_fast(float x) {
    float t = 0.7978845608028654f * x * (1.0f + 0.044715f * x * x);
    float e = __expf(2.0f * t);
    return x * (1.0f - __builtin_amdgcn_rcpf(e + 1.0f));
}
__device__ __forceinline__ float sigmoid_fast(float x) {
    return __builtin_amdgcn_rcpf(1.0f + __expf(-x));
}
__device__ __forceinline__ float bflo(unsigned v) { return __uint_as_float(v << 16); }
__device__ __forceinline__ float bfhi(unsigned v) { return __uint_as_float(v & 0xFFFF0000u); }

// ---------------- one-shot: build bf16 B-fragment tables for W_src, W_dst, Wg1
// frag layout: [kb][nt][lane][e] ; value = W[kb*32 + (lane>>4)*8 + e][nt*16 + (lane&15)]
__global__ __launch_bounds__(256) void k_prep(
    const float* __restrict__ Ws, const float* __restrict__ Wd,
    const float* __restrict__ Wg1, short* __restrict__ frag)
{
    int g = blockIdx.x * 256 + threadIdx.x;
    if (g >= 5120) return;
    const float* W; short* T; int q;
    if (g < 2048)      { W = Ws;  T = frag;         q = g; }
    else if (g < 4096) { W = Wd;  T = frag + 16384; q = g - 2048; }
    else               { W = Wg1; T = frag + 32768; q = g - 4096; }
    int ls = q & 63, nt = (q >> 6) & 7, kb = q >> 9;
    int col = nt * 16 + (ls & 15);
    int k0 = kb * 32 + (ls >> 4) * 8;
    bf16x8 v;
    #pragma unroll
    for (int e = 0; e < 8; ++e) v[e] = f2bf(W[(k0 + e) * D_MODEL + col]);
    *reinterpret_cast<bf16x8*>(T + (size_t)q * 8) = v;
}

// ---------------- y_src = x_src@W_src (bf16 out), z = x_dst@W_dst + b_dst (f32 out)
__global__ __launch_bounds__(256, 2) void k_node_linear(
    const float* __restrict__ x_src, const float* __restrict__ x_dst,
    const short* __restrict__ WsrcF, const short* __restrict__ WdstF,
    const float* __restrict__ b_dst,
    short* __restrict__ ysrc, float* __restrict__ z)
{
    __shared__ __align__(16) short Bf[4][8][64][8];  // 32 KB
    const int tid = threadIdx.x;
    const int lane = tid & 63;
    const int wid = tid >> 6;
    const int l15 = lane & 15;
    const int lg = lane >> 4;
    const int mat = blockIdx.y;
    const float* __restrict__ X = mat ? x_dst : x_src;
    const short* __restrict__ WF = mat ? WdstF : WsrcF;
    const int row0 = blockIdx.x * 128 + wid * 32;

    // issue A loads early
    float4 av[4][2][2];
    #pragma unroll
    for (int kb = 0; kb < 4; ++kb)
        #pragma unroll
        for (int st = 0; st < 2; ++st) {
            int r = min(row0 + st * 16 + l15, N_NODES - 1);
            const float* p = X + (size_t)r * D_MODEL + kb * 32 + lg * 8;
            av[kb][st][0] = *reinterpret_cast<const float4*>(p);
            av[kb][st][1] = *reinterpret_cast<const float4*>(p + 4);
        }
    // stage fragment table (contiguous copy)
    #pragma unroll
    for (int i = 0; i < 8; ++i)
        reinterpret_cast<int4*>(Bf)[tid + i * 256] =
            reinterpret_cast<const int4*>(WF)[tid + i * 256];
    __syncthreads();

    bf16x8 a[4][2];
    #pragma unroll
    for (int kb = 0; kb < 4; ++kb)
        #pragma unroll
        for (int st = 0; st < 2; ++st) {
            float4 v0 = av[kb][st][0], v1 = av[kb][st][1];
            bf16x8 t;
            t[0] = f2bf(v0.x); t[1] = f2bf(v0.y); t[2] = f2bf(v0.z); t[3] = f2bf(v0.w);
            t[4] = f2bf(v1.x); t[5] = f2bf(v1.y); t[6] = f2bf(v1.z); t[7] = f2bf(v1.w);
            a[kb][st] = t;
        }

    f32x4 acc[2][8];
    #pragma unroll
    for (int st = 0; st < 2; ++st)
        #pragma unroll
        for (int nt = 0; nt < 8; ++nt) { f32x4 zz = {0.f,0.f,0.f,0.f}; acc[st][nt] = zz; }

    #pragma unroll
    for (int kb = 0; kb < 4; ++kb)
        #pragma unroll
        for (int nt = 0; nt < 8; ++nt) {
            bf16x8 b = *reinterpret_cast<const bf16x8*>(&Bf[kb][nt][lane][0]);
            acc[0][nt] = __builtin_amdgcn_mfma_f32_16x16x32_bf16(a[kb][0], b, acc[0][nt], 0, 0, 0);
            acc[1][nt] = __builtin_amdgcn_mfma_f32_16x16x32_bf16(a[kb][1], b, acc[1][nt], 0, 0, 0);
        }

    #pragma unroll
    for (int st = 0; st < 2; ++st) {
        int rowb = row0 + st * 16 + lg * 4;
        #pragma unroll
        for (int nt = 0; nt < 8; ++nt) {
            int col = nt * 16 + l15;
            float bias = mat ? b_dst[col] : 0.0f;
            #pragma unroll
            for (int r = 0; r < 4; ++r) {
                int row = rowb + r;
                if (row < N_NODES) {
                    float v = acc[st][nt][r];
                    if (mat) z[(size_t)row * D_MODEL + col] = v + bias;
                    else     ysrc[(size_t)row * D_MODEL + col] = f2bf(v);
                }
            }
        }
    }
}

// ---------------- gate_h[e] = sigmoid(gelu(ea@Wg1+bg1)@Wg2+bg2), half out
__global__ __launch_bounds__(256, 4) void k_gate(
    const float* __restrict__ ea, const short* __restrict__ Wg1F,
    const float* __restrict__ bg1, const float* __restrict__ Wg2,
    const float* __restrict__ bg2, __half* __restrict__ gate_h)
{
    __shared__ __align__(16) short Bf[2][8][64][8];  // 16 KB
    const int tid = threadIdx.x;
    const int lane = tid & 63;
    const int wid = tid >> 6;
    const int l15 = lane & 15;
    const int lg = lane >> 4;
    const int e0 = blockIdx.x * 128 + wid * 32;

    // issue A loads early
    float4 av[2][2][2];
    #pragma unroll
    for (int kb = 0; kb < 2; ++kb)
        #pragma unroll
        for (int st = 0; st < 2; ++st) {
            int r = min(e0 + st * 16 + l15, N_EDGES - 1);
            const float* p = ea + (size_t)r * EDGE_DIM + kb * 32 + lg * 8;
            av[kb][st][0] = *reinterpret_cast<const float4*>(p);
            av[kb][st][1] = *reinterpret_cast<const float4*>(p + 4);
        }
    // prefetch epilogue vectors
    float b1v[2][4], w2v[2][4];
    #pragma unroll
    for (int ntc = 0; ntc < 2; ++ntc)
        #pragma unroll
        for (int nt = 0; nt < 4; ++nt) {
            int col = (ntc * 4 + nt) * 16 + l15;
            b1v[ntc][nt] = bg1[col];
            w2v[ntc][nt] = Wg2[col];
        }
    // stage Wg1 fragment table
    #pragma unroll
    for (int i = 0; i < 4; ++i)
        reinterpret_cast<int4*>(Bf)[tid + i * 256] =
            reinterpret_cast<const int4*>(Wg1F)[tid + i * 256];
    __syncthreads();

    bf16x8 a[2][2];
    #pragma unroll
    for (int kb = 0; kb < 2; ++kb)
        #pragma unroll
        for (int st = 0; st < 2; ++st) {
            float4 v0 = av[kb][st][0], v1 = av[kb][st][1];
            bf16x8 t;
            t[0] = f2bf(v0.x); t[1] = f2bf(v0.y); t[2] = f2bf(v0.z); t[3] = f2bf(v0.w);
            t[4] = f2bf(v1.x); t[5] = f2bf(v1.y); t[6] = f2bf(v1.z); t[7] = f2bf(v1.w);
            a[kb][st] = t;
        }

    float part[2][4] = {{0.f,0.f,0.f,0.f},{0.f,0.f,0.f,0.f}};
    #pragma unroll
    for (int ntc = 0; ntc < 2; ++ntc) {
        f32x4 acc[2][4];
        #pragma unroll
        for (int st = 0; st < 2; ++st)
            #pragma unroll
            for (int nt = 0; nt < 4; ++nt) { f32x4 zz = {0.f,0.f,0.f,0.f}; acc[st][nt] = zz; }
        #pragma unroll
        for (int kb = 0; kb < 2; ++kb)
            #pragma unroll
            for (int nt = 0; nt < 4; ++nt) {
                bf16x8 b = *reinterpret_cast<const bf16x8*>(&Bf[kb][ntc * 4 + nt][lane][0]);
                acc[0][nt] = __builtin_amdgcn_mfma_f32_16x16x32_bf16(a[kb][0], b, acc[0][nt], 0, 0, 0);
                acc[1][nt] = __builtin_amdgcn_mfma_f32_16x16x32_bf16(a[kb][1], b, acc[1][nt], 0, 0, 0);
            }
        #pragma unroll
        for (int nt = 0; nt < 4; ++nt) {
            float b1 = b1v[ntc][nt], w2 = w2v[ntc][nt];
            #pragma unroll
            for (int st = 0; st < 2; ++st)
                #pragma unroll
                for (int r = 0; r < 4; ++r)
                    part[st][r] += gelu_fast(acc[st][nt][r] + b1) * w2;
        }
    }

    #pragma unroll
    for (int m = 1; m <= 8; m <<= 1)
        #pragma unroll
        for (int st = 0; st < 2; ++st)
            #pragma unroll
            for (int r = 0; r < 4; ++r)
                part[st][r] += __shfl_xor(part[st][r], m);

    if (l15 == 0) {
        float b2 = bg2[0];
        #pragma unroll
        for (int st = 0; st < 2; ++st)
            #pragma unroll
            for (int r = 0; r < 4; ++r) {
                int e = e0 + st * 16 + lg * 4 + r;
                if (e < N_EDGES) gate_h[e] = __float2half(sigmoid_fast(part[st][r] + b2));
            }
    }
}

// ---------------- CSR build
__global__ void k_deg(const int* __restrict__ dst, int* __restrict__ deg) {
    int e = blockIdx.x * 256 + threadIdx.x;
    if (e < N_EDGES) atomicAdd(&deg[dst[e]], 1);
}
__global__ __launch_bounds__(256) void k_scan1(const int* __restrict__ deg, int* __restrict__ bsum) {
    __shared__ int s[256];
    int tid = threadIdx.x;
    int i = blockIdx.x * SCHUNK + tid;
    int v = (tid < SCHUNK && i < N_NODES) ? deg[i] : 0;
    s[tid] = v; __syncthreads();
    for (int off = 128; off > 0; off >>= 1) {
        if (tid < off) s[tid] += s[tid + off];
        __syncthreads();
    }
    if (tid == 0) bsum[blockIdx.x] = s[0];
}
__global__ __launch_bounds__(512) void k_scan2(const int* __restrict__ bsum, int* __restrict__ boff) {
    __shared__ int s[512];
    int tid = threadIdx.x;
    int v = (tid < NSB) ? bsum[tid] : 0;
    s[tid] = v; __syncthreads();
    for (int off = 1; off < 512; off <<= 1) {
        int t = (tid >= off) ? s[tid - off] : 0;
        __syncthreads();
        s[tid] += t;
        __syncthreads();
    }
    if (tid < NSB) boff[tid] = s[tid] - v;
}
__global__ __launch_bounds__(256) void k_scan3(const int* __restrict__ deg, const int* __restrict__ boff,
                                               int* __restrict__ cursor) {
    __shared__ int s[256];
    int tid = threadIdx.x;
    int i = blockIdx.x * SCHUNK + tid;
    int v = (tid < SCHUNK && i < N_NODES) ? deg[i] : 0;
    s[tid] = v; __syncthreads();
    for (int off = 1; off < 256; off <<= 1) {
        int t = (tid >= off) ? s[tid - off] : 0;
        __syncthreads();
        s[tid] += t;
        __syncthreads();
    }
    int excl = s[tid] - v;
    if (tid < SCHUNK && i < N_NODES) cursor[i] = boff[blockIdx.x] + excl;
}
// scatter (src, gate) into CSR slot order; cursor ends at row-end
__global__ void k_fill(const int* __restrict__ dst, const int* __restrict__ srcI,
                       const unsigned short* __restrict__ gate_h, int* __restrict__ cursor,
                       int* __restrict__ sg_s, unsigned short* __restrict__ sg_g) {
    int e = blockIdx.x * 256 + threadIdx.x;
    if (e < N_EDGES) {
        int d = dst[e];
        int p = atomicAdd(&cursor[d], 1);
        sg_s[p] = srcI[e];
        sg_g[p] = gate_h[e];
    }
}

// ---------------- per-node gather + mean + residual + LN + GELU (one wave per node)
__global__ __launch_bounds__(256) void k_agg(
    const int* __restrict__ cursorEnd, const int* __restrict__ deg,
    const int* __restrict__ sg_s, const __half* __restrict__ sg_g,
    const short* __restrict__ ysrc, const float* __restrict__ z,
    const float* __restrict__ gamma, const float* __restrict__ beta,
    float* __restrict__ out)
{
    const int lane = threadIdx.x & 63;
    const int wid = threadIdx.x >> 6;
    const int n = blockIdx.x * 4 + wid;
    const int dg = deg[n];
    const int start = cursorEnd[n] - dg;
    const int c0 = lane * 2;

    float a0 = 0.f, a1 = 0.f;
    int t = 0;
    for (; t + 4 <= dg; t += 4) {
        int s0 = sg_s[start + t + 0];
        int s1 = sg_s[start + t + 1];
        int s2 = sg_s[start + t + 2];
        int s3 = sg_s[start + t + 3];
        float g0 = __half2float(sg_g[start + t + 0]);
        float g1 = __half2float(sg_g[start + t + 1]);
        float g2 = __half2float(sg_g[start + t + 2]);
        float g3 = __half2float(sg_g[start + t + 3]);
        unsigned p0 = *reinterpret_cast<const unsigned*>(&ysrc[(size_t)s0 * D_MODEL + c0]);
        unsigned p1 = *reinterpret_cast<const unsigned*>(&ysrc[(size_t)s1 * D_MODEL + c0]);
        unsigned p2 = *reinterpret_cast<const unsigned*>(&ysrc[(size_t)s2 * D_MODEL + c0]);
        unsigned p3 = *reinterpret_cast<const unsigned*>(&ysrc[(size_t)s3 * D_MODEL + c0]);
        a0 += g0 * bflo(p0) + g1 * bflo(p1) + g2 * bflo(p2) + g3 * bflo(p3);
        a1 += g0 * bfhi(p0) + g1 * bfhi(p1) + g2 * bfhi(p2) + g3 * bfhi(p3);
    }
    for (; t < dg; ++t) {
        int s0 = sg_s[start + t];
        float g0 = __half2float(sg_g[start + t]);
        unsigned p0 = *reinterpret_cast<const unsigned*>(&ysrc[(size_t)s0 * D_MODEL + c0]);
        a0 += g0 * bflo(p0);
        a1 += g0 * bfhi(p0);
    }

    float inv = 1.0f / fmaxf((float)dg, 1.0f);
    float2 zv = *reinterpret_cast<const float2*>(&z[(size_t)n * D_MODEL + c0]);
    float t0 = a0 * inv + zv.x;
    float t1 = a1 * inv + zv.y;

    float sum = t0 + t1;
    #pragma unroll
    for (int m = 1; m <= 32; m <<= 1) sum += __shfl_xor(sum, m);
    float mu = sum * (1.0f / 128.0f);
    float d0 = t0 - mu, d1 = t1 - mu;
    float vs = d0 * d0 + d1 * d1;
    #pragma unroll
    for (int m = 1; m <= 32; m <<= 1) vs += __shfl_xor(vs, m);
    float rstd = rsqrtf(vs * (1.0f / 128.0f) + 1e-5f);

    float2 gv = *reinterpret_cast<const float2*>(&gamma[c0]);
    float2 bv = *reinterpret_cast<const float2*>(&beta[c0]);
    float o0 = d0 * rstd * gv.x + bv.x;
    float o1 = d1 * rstd * gv.y + bv.y;
    float2 o = make_float2(gelu_fast(o0), gelu_fast(o1));
    *reinterpret_cast<float2*>(&out[(size_t)n * D_MODEL + c0]) = o;
}

extern "C" void kernel_launch(void* const* d_in, const int* in_sizes, int n_in,
                              void* d_out, int out_size, void* d_ws, size_t ws_size,
                              hipStream_t stream)
{
    const float* x_src = (const float*)d_in[0];
    const float* x_dst = (const float*)d_in[1];
    const float* ea    = (const float*)d_in[2];
    const int*   ei    = (const int*)d_in[3];
    const float* W_src = (const float*)d_in[4];
    const float* W_dst = (const float*)d_in[5];
    const float* b_dst = (const float*)d_in[6];
    const float* Wg1   = (const float*)d_in[7];
    const float* bg1   = (const float*)d_in[8];
    const float* Wg2   = (const float*)d_in[9];
    const float* bg2   = (const float*)d_in[10];
    const float* gamma = (const float*)d_in[11];
    const float* beta  = (const float*)d_in[12];
    const int* srcIdx = ei;
    const int* dstIdx = ei + N_EDGES;

    char* ws = (char*)d_ws;
    short*  fragT  = (short*)(ws);                   // 81,920 B (WsrcF | WdstF | Wg1F)
    short*  ysrc   = (short*)(ws + 81920);           // 25,600,000 B
    float*  z      = (float*)(ws + 25681920);        // 51,200,000 B
    __half* gate_h = (__half*)(ws + 76881920);       //  2,000,000 B
    int*    deg    = (int*)(ws + 78881920);          //    400,000 B
    int*    cursor = (int*)(ws + 79281920);          //    400,000 B
    int*    sg_s   = (int*)(ws + 79681920);          //  4,000,000 B
    unsigned short* sg_g = (unsigned short*)(ws + 83681920); // 2,000,000 B
    int*    bsum   = (int*)(ws + 85681920);          //      1,600 B
    int*    boff   = (int*)(ws + 85683520);          //      1,600 B

    float* out = (float*)d_out;

    (void)hipMemsetAsync(deg, 0, N_NODES * sizeof(int), stream);
    hipLaunchKernelGGL(k_prep, dim3(20), dim3(256), 0, stream, W_src, W_dst, Wg1, fragT);
    hipLaunchKernelGGL(k_node_linear, dim3(782, 2), dim3(256), 0, stream,
                       x_src, x_dst, fragT, fragT + 16384, b_dst, ysrc, z);
    hipLaunchKernelGGL(k_gate, dim3(7813), dim3(256), 0, stream,
                       ea, fragT + 32768, bg1, Wg2, bg2, gate_h);
    hipLaunchKernelGGL(k_deg, dim3(3907), dim3(256), 0, stream, dstIdx, deg);
    hipLaunchKernelGGL(k_scan1, dim3(NSB), dim3(256), 0, stream, deg, bsum);
    hipLaunchKernelGGL(k_scan2, dim3(1), dim3(512), 0, stream, bsum, boff);
    hipLaunchKernelGGL(k_scan3, dim3(NSB), dim3(256), 0, stream, deg, boff, cursor);
    hipLaunchKernelGGL(k_fill, dim3(3907), dim3(256), 0, stream,
                       dstIdx, srcIdx, (const unsigned short*)gate_h, cursor, sg_s, sg_g);
    hipLaunchKernelGGL(k_agg, dim3(N_NODES / 4), dim3(256), 0, stream,
                       cursor, deg, sg_s, (const __half*)sg_g, ysrc, z, gamma, beta, out);
}

// Round 4
// 308.648 us; speedup vs baseline: 2.2214x; 1.0030x over previous
//
#include <hip/hip_runtime.h>
#include <hip/hip_fp16.h>
#include <math.h>

#define N_NODES 100000
#define N_EDGES 1000000
#define D_MODEL 128
#define EDGE_DIM 64
#define SCHUNK 250
#define NSB 400

typedef short bf16x8 __attribute__((ext_vector_type(8)));
typedef float f32x4 __attribute__((ext_vector_type(4)));

__device__ __forceinline__ short f2bf(float f) {
    union { float f; unsigned u; } v; v.f = f;
    unsigned r = v.u + 0x7FFFu + ((v.u >> 16) & 1u);
    return (short)(r >> 16);
}
// tanh-form GELU: x*sigmoid(2t), t = 0.79788456(x + 0.044715 x^3). Max abs dev ~4e-4.
__device__ __forceinline__ float gelu_fast(float x) {
    float t = 0.7978845608028654f * x * (1.0f + 0.044715f * x * x);
    float e = __expf(2.0f * t);
    return x * (1.0f - __builtin_amdgcn_rcpf(e + 1.0f));
}
__device__ __forceinline__ float sigmoid_fast(float x) {
    return __builtin_amdgcn_rcpf(1.0f + __expf(-x));
}
__device__ __forceinline__ float bflo(unsigned v) { return __uint_as_float(v << 16); }
__device__ __forceinline__ float bfhi(unsigned v) { return __uint_as_float(v & 0xFFFF0000u); }

// ---------------- zero deg (replaces hipMemsetAsync: rocclr fill burned ~144us/replay)
__global__ __launch_bounds__(256) void k_zero_int(int* __restrict__ p, int n) {
    int i = blockIdx.x * 256 + threadIdx.x;
    if (i < n) p[i] = 0;
}

// ---------------- one-shot: build bf16 B-fragment tables for W_src, W_dst, Wg1
// frag layout: [kb][nt][lane][e] ; value = W[kb*32 + (lane>>4)*8 + e][nt*16 + (lane&15)]
__global__ __launch_bounds__(256) void k_prep(
    const float* __restrict__ Ws, const float* __restrict__ Wd,
    const float* __restrict__ Wg1, short* __restrict__ frag)
{
    int g = blockIdx.x * 256 + threadIdx.x;
    if (g >= 5120) return;
    const float* W; short* T; int q;
    if (g < 2048)      { W = Ws;  T = frag;         q = g; }
    else if (g < 4096) { W = Wd;  T = frag + 16384; q = g - 2048; }
    else               { W = Wg1; T = frag + 32768; q = g - 4096; }
    int ls = q & 63, nt = (q >> 6) & 7, kb = q >> 9;
    int col = nt * 16 + (ls & 15);
    int k0 = kb * 32 + (ls >> 4) * 8;
    bf16x8 v;
    #pragma unroll
    for (int e = 0; e < 8; ++e) v[e] = f2bf(W[(k0 + e) * D_MODEL + col]);
    *reinterpret_cast<bf16x8*>(T + (size_t)q * 8) = v;
}

// ---------------- y_src = x_src@W_src (bf16 out), z = x_dst@W_dst + b_dst (f32 out)
__global__ __launch_bounds__(256, 2) void k_node_linear(
    const float* __restrict__ x_src, const float* __restrict__ x_dst,
    const short* __restrict__ WsrcF, const short* __restrict__ WdstF,
    const float* __restrict__ b_dst,
    short* __restrict__ ysrc, float* __restrict__ z)
{
    __shared__ __align__(16) short Bf[4][8][64][8];  // 32 KB
    const int tid = threadIdx.x;
    const int lane = tid & 63;
    const int wid = tid >> 6;
    const int l15 = lane & 15;
    const int lg = lane >> 4;
    const int mat = blockIdx.y;
    const float* __restrict__ X = mat ? x_dst : x_src;
    const short* __restrict__ WF = mat ? WdstF : WsrcF;
    const int row0 = blockIdx.x * 128 + wid * 32;

    // issue A loads early
    float4 av[4][2][2];
    #pragma unroll
    for (int kb = 0; kb < 4; ++kb)
        #pragma unroll
        for (int st = 0; st < 2; ++st) {
            int r = min(row0 + st * 16 + l15, N_NODES - 1);
            const float* p = X + (size_t)r * D_MODEL + kb * 32 + lg * 8;
            av[kb][st][0] = *reinterpret_cast<const float4*>(p);
            av[kb][st][1] = *reinterpret_cast<const float4*>(p + 4);
        }
    // stage fragment table (contiguous copy)
    #pragma unroll
    for (int i = 0; i < 8; ++i)
        reinterpret_cast<int4*>(Bf)[tid + i * 256] =
            reinterpret_cast<const int4*>(WF)[tid + i * 256];
    __syncthreads();

    bf16x8 a[4][2];
    #pragma unroll
    for (int kb = 0; kb < 4; ++kb)
        #pragma unroll
        for (int st = 0; st < 2; ++st) {
            float4 v0 = av[kb][st][0], v1 = av[kb][st][1];
            bf16x8 t;
            t[0] = f2bf(v0.x); t[1] = f2bf(v0.y); t[2] = f2bf(v0.z); t[3] = f2bf(v0.w);
            t[4] = f2bf(v1.x); t[5] = f2bf(v1.y); t[6] = f2bf(v1.z); t[7] = f2bf(v1.w);
            a[kb][st] = t;
        }

    f32x4 acc[2][8];
    #pragma unroll
    for (int st = 0; st < 2; ++st)
        #pragma unroll
        for (int nt = 0; nt < 8; ++nt) { f32x4 zz = {0.f,0.f,0.f,0.f}; acc[st][nt] = zz; }

    #pragma unroll
    for (int kb = 0; kb < 4; ++kb)
        #pragma unroll
        for (int nt = 0; nt < 8; ++nt) {
            bf16x8 b = *reinterpret_cast<const bf16x8*>(&Bf[kb][nt][lane][0]);
            acc[0][nt] = __builtin_amdgcn_mfma_f32_16x16x32_bf16(a[kb][0], b, acc[0][nt], 0, 0, 0);
            acc[1][nt] = __builtin_amdgcn_mfma_f32_16x16x32_bf16(a[kb][1], b, acc[1][nt], 0, 0, 0);
        }

    #pragma unroll
    for (int st = 0; st < 2; ++st) {
        int rowb = row0 + st * 16 + lg * 4;
        #pragma unroll
        for (int nt = 0; nt < 8; ++nt) {
            int col = nt * 16 + l15;
            float bias = mat ? b_dst[col] : 0.0f;
            #pragma unroll
            for (int r = 0; r < 4; ++r) {
                int row = rowb + r;
                if (row < N_NODES) {
                    float v = acc[st][nt][r];
                    if (mat) z[(size_t)row * D_MODEL + col] = v + bias;
                    else     ysrc[(size_t)row * D_MODEL + col] = f2bf(v);
                }
            }
        }
    }
}

// ---------------- gate_h[e] = sigmoid(gelu(ea@Wg1+bg1)@Wg2+bg2), half out
__global__ __launch_bounds__(256, 4) void k_gate(
    const float* __restrict__ ea, const short* __restrict__ Wg1F,
    const float* __restrict__ bg1, const float* __restrict__ Wg2,
    const float* __restrict__ bg2, __half* __restrict__ gate_h)
{
    __shared__ __align__(16) short Bf[2][8][64][8];  // 16 KB
    const int tid = threadIdx.x;
    const int lane = tid & 63;
    const int wid = tid >> 6;
    const int l15 = lane & 15;
    const int lg = lane >> 4;
    const int e0 = blockIdx.x * 128 + wid * 32;

    // issue A loads early
    float4 av[2][2][2];
    #pragma unroll
    for (int kb = 0; kb < 2; ++kb)
        #pragma unroll
        for (int st = 0; st < 2; ++st) {
            int r = min(e0 + st * 16 + l15, N_EDGES - 1);
            const float* p = ea + (size_t)r * EDGE_DIM + kb * 32 + lg * 8;
            av[kb][st][0] = *reinterpret_cast<const float4*>(p);
            av[kb][st][1] = *reinterpret_cast<const float4*>(p + 4);
        }
    // prefetch epilogue vectors
    float b1v[2][4], w2v[2][4];
    #pragma unroll
    for (int ntc = 0; ntc < 2; ++ntc)
        #pragma unroll
        for (int nt = 0; nt < 4; ++nt) {
            int col = (ntc * 4 + nt) * 16 + l15;
            b1v[ntc][nt] = bg1[col];
            w2v[ntc][nt] = Wg2[col];
        }
    // stage Wg1 fragment table
    #pragma unroll
    for (int i = 0; i < 4; ++i)
        reinterpret_cast<int4*>(Bf)[tid + i * 256] =
            reinterpret_cast<const int4*>(Wg1F)[tid + i * 256];
    __syncthreads();

    bf16x8 a[2][2];
    #pragma unroll
    for (int kb = 0; kb < 2; ++kb)
        #pragma unroll
        for (int st = 0; st < 2; ++st) {
            float4 v0 = av[kb][st][0], v1 = av[kb][st][1];
            bf16x8 t;
            t[0] = f2bf(v0.x); t[1] = f2bf(v0.y); t[2] = f2bf(v0.z); t[3] = f2bf(v0.w);
            t[4] = f2bf(v1.x); t[5] = f2bf(v1.y); t[6] = f2bf(v1.z); t[7] = f2bf(v1.w);
            a[kb][st] = t;
        }

    float part[2][4] = {{0.f,0.f,0.f,0.f},{0.f,0.f,0.f,0.f}};
    #pragma unroll
    for (int ntc = 0; ntc < 2; ++ntc) {
        f32x4 acc[2][4];
        #pragma unroll
        for (int st = 0; st < 2; ++st)
            #pragma unroll
            for (int nt = 0; nt < 4; ++nt) { f32x4 zz = {0.f,0.f,0.f,0.f}; acc[st][nt] = zz; }
        #pragma unroll
        for (int kb = 0; kb < 2; ++kb)
            #pragma unroll
            for (int nt = 0; nt < 4; ++nt) {
                bf16x8 b = *reinterpret_cast<const bf16x8*>(&Bf[kb][ntc * 4 + nt][lane][0]);
                acc[0][nt] = __builtin_amdgcn_mfma_f32_16x16x32_bf16(a[kb][0], b, acc[0][nt], 0, 0, 0);
                acc[1][nt] = __builtin_amdgcn_mfma_f32_16x16x32_bf16(a[kb][1], b, acc[1][nt], 0, 0, 0);
            }
        #pragma unroll
        for (int nt = 0; nt < 4; ++nt) {
            float b1 = b1v[ntc][nt], w2 = w2v[ntc][nt];
            #pragma unroll
            for (int st = 0; st < 2; ++st)
                #pragma unroll
                for (int r = 0; r < 4; ++r)
                    part[st][r] += gelu_fast(acc[st][nt][r] + b1) * w2;
        }
    }

    #pragma unroll
    for (int m = 1; m <= 8; m <<= 1)
        #pragma unroll
        for (int st = 0; st < 2; ++st)
            #pragma unroll
            for (int r = 0; r < 4; ++r)
                part[st][r] += __shfl_xor(part[st][r], m);

    if (l15 == 0) {
        float b2 = bg2[0];
        #pragma unroll
        for (int st = 0; st < 2; ++st)
            #pragma unroll
            for (int r = 0; r < 4; ++r) {
                int e = e0 + st * 16 + lg * 4 + r;
                if (e < N_EDGES) gate_h[e] = __float2half(sigmoid_fast(part[st][r] + b2));
            }
    }
}

// ---------------- CSR build
__global__ void k_deg(const int* __restrict__ dst, int* __restrict__ deg) {
    int e = blockIdx.x * 256 + threadIdx.x;
    if (e < N_EDGES) atomicAdd(&deg[dst[e]], 1);
}
__global__ __launch_bounds__(256) void k_scan1(const int* __restrict__ deg, int* __restrict__ bsum) {
    __shared__ int s[256];
    int tid = threadIdx.x;
    int i = blockIdx.x * SCHUNK + tid;
    int v = (tid < SCHUNK && i < N_NODES) ? deg[i] : 0;
    s[tid] = v; __syncthreads();
    for (int off = 128; off > 0; off >>= 1) {
        if (tid < off) s[tid] += s[tid + off];
        __syncthreads();
    }
    if (tid == 0) bsum[blockIdx.x] = s[0];
}
__global__ __launch_bounds__(512) void k_scan2(const int* __restrict__ bsum, int* __restrict__ boff) {
    __shared__ int s[512];
    int tid = threadIdx.x;
    int v = (tid < NSB) ? bsum[tid] : 0;
    s[tid] = v; __syncthreads();
    for (int off = 1; off < 512; off <<= 1) {
        int t = (tid >= off) ? s[tid - off] : 0;
        __syncthreads();
        s[tid] += t;
        __syncthreads();
    }
    if (tid < NSB) boff[tid] = s[tid] - v;
}
__global__ __launch_bounds__(256) void k_scan3(const int* __restrict__ deg, const int* __restrict__ boff,
                                               int* __restrict__ cursor) {
    __shared__ int s[256];
    int tid = threadIdx.x;
    int i = blockIdx.x * SCHUNK + tid;
    int v = (tid < SCHUNK && i < N_NODES) ? deg[i] : 0;
    s[tid] = v; __syncthreads();
    for (int off = 1; off < 256; off <<= 1) {
        int t = (tid >= off) ? s[tid - off] : 0;
        __syncthreads();
        s[tid] += t;
        __syncthreads();
    }
    int excl = s[tid] - v;
    if (tid < SCHUNK && i < N_NODES) cursor[i] = boff[blockIdx.x] + excl;
}
// scatter (src, gate) into CSR slot order; cursor ends at row-end
__global__ void k_fill(const int* __restrict__ dst, const int* __restrict__ srcI,
                       const unsigned short* __restrict__ gate_h, int* __restrict__ cursor,
                       int* __restrict__ sg_s, unsigned short* __restrict__ sg_g) {
    int e = blockIdx.x * 256 + threadIdx.x;
    if (e < N_EDGES) {
        int d = dst[e];
        int p = atomicAdd(&cursor[d], 1);
        sg_s[p] = srcI[e];
        sg_g[p] = gate_h[e];
    }
}

// ---------------- per-node gather + mean + residual + LN + GELU (one wave per node)
__global__ __launch_bounds__(256) void k_agg(
    const int* __restrict__ cursorEnd, const int* __restrict__ deg,
    const int* __restrict__ sg_s, const __half* __restrict__ sg_g,
    const short* __restrict__ ysrc, const float* __restrict__ z,
    const float* __restrict__ gamma, const float* __restrict__ beta,
    float* __restrict__ out)
{
    const int lane = threadIdx.x & 63;
    const int wid = threadIdx.x >> 6;
    const int n = blockIdx.x * 4 + wid;
    const int dg = deg[n];
    const int start = cursorEnd[n] - dg;
    const int c0 = lane * 2;

    float a0 = 0.f, a1 = 0.f;
    int t = 0;
    for (; t + 4 <= dg; t += 4) {
        int s0 = sg_s[start + t + 0];
        int s1 = sg_s[start + t + 1];
        int s2 = sg_s[start + t + 2];
        int s3 = sg_s[start + t + 3];
        float g0 = __half2float(sg_g[start + t + 0]);
        float g1 = __half2float(sg_g[start + t + 1]);
        float g2 = __half2float(sg_g[start + t + 2]);
        float g3 = __half2float(sg_g[start + t + 3]);
        unsigned p0 = *reinterpret_cast<const unsigned*>(&ysrc[(size_t)s0 * D_MODEL + c0]);
        unsigned p1 = *reinterpret_cast<const unsigned*>(&ysrc[(size_t)s1 * D_MODEL + c0]);
        unsigned p2 = *reinterpret_cast<const unsigned*>(&ysrc[(size_t)s2 * D_MODEL + c0]);
        unsigned p3 = *reinterpret_cast<const unsigned*>(&ysrc[(size_t)s3 * D_MODEL + c0]);
        a0 += g0 * bflo(p0) + g1 * bflo(p1) + g2 * bflo(p2) + g3 * bflo(p3);
        a1 += g0 * bfhi(p0) + g1 * bfhi(p1) + g2 * bfhi(p2) + g3 * bfhi(p3);
    }
    for (; t < dg; ++t) {
        int s0 = sg_s[start + t];
        float g0 = __half2float(sg_g[start + t]);
        unsigned p0 = *reinterpret_cast<const unsigned*>(&ysrc[(size_t)s0 * D_MODEL + c0]);
        a0 += g0 * bflo(p0);
        a1 += g0 * bfhi(p0);
    }

    float inv = 1.0f / fmaxf((float)dg, 1.0f);
    float2 zv = *reinterpret_cast<const float2*>(&z[(size_t)n * D_MODEL + c0]);
    float t0 = a0 * inv + zv.x;
    float t1 = a1 * inv + zv.y;

    float sum = t0 + t1;
    #pragma unroll
    for (int m = 1; m <= 32; m <<= 1) sum += __shfl_xor(sum, m);
    float mu = sum * (1.0f / 128.0f);
    float d0 = t0 - mu, d1 = t1 - mu;
    float vs = d0 * d0 + d1 * d1;
    #pragma unroll
    for (int m = 1; m <= 32; m <<= 1) vs += __shfl_xor(vs, m);
    float rstd = rsqrtf(vs * (1.0f / 128.0f) + 1e-5f);

    float2 gv = *reinterpret_cast<const float2*>(&gamma[c0]);
    float2 bv = *reinterpret_cast<const float2*>(&beta[c0]);
    float o0 = d0 * rstd * gv.x + bv.x;
    float o1 = d1 * rstd * gv.y + bv.y;
    float2 o = make_float2(gelu_fast(o0), gelu_fast(o1));
    *reinterpret_cast<float2*>(&out[(size_t)n * D_MODEL + c0]) = o;
}

extern "C" void kernel_launch(void* const* d_in, const int* in_sizes, int n_in,
                              void* d_out, int out_size, void* d_ws, size_t ws_size,
                              hipStream_t stream)
{
    const float* x_src = (const float*)d_in[0];
    const float* x_dst = (const float*)d_in[1];
    const float* ea    = (const float*)d_in[2];
    const int*   ei    = (const int*)d_in[3];
    const float* W_src = (const float*)d_in[4];
    const float* W_dst = (const float*)d_in[5];
    const float* b_dst = (const float*)d_in[6];
    const float* Wg1   = (const float*)d_in[7];
    const float* bg1   = (const float*)d_in[8];
    const float* Wg2   = (const float*)d_in[9];
    const float* bg2   = (const float*)d_in[10];
    const float* gamma = (const float*)d_in[11];
    const float* beta  = (const float*)d_in[12];
    const int* srcIdx = ei;
    const int* dstIdx = ei + N_EDGES;

    char* ws = (char*)d_ws;
    short*  fragT  = (short*)(ws);                   // 81,920 B (WsrcF | WdstF | Wg1F)
    short*  ysrc   = (short*)(ws + 81920);           // 25,600,000 B
    float*  z      = (float*)(ws + 25681920);        // 51,200,000 B
    __half* gate_h = (__half*)(ws + 76881920);       //  2,000,000 B
    int*    deg    = (int*)(ws + 78881920);          //    400,000 B
    int*    cursor = (int*)(ws + 79281920);          //    400,000 B
    int*    sg_s   = (int*)(ws + 79681920);          //  4,000,000 B
    unsigned short* sg_g = (unsigned short*)(ws + 83681920); // 2,000,000 B
    int*    bsum   = (int*)(ws + 85681920);          //      1,600 B
    int*    boff   = (int*)(ws + 85683520);          //      1,600 B

    float* out = (float*)d_out;

    hipLaunchKernelGGL(k_zero_int, dim3((N_NODES + 255) / 256), dim3(256), 0, stream, deg, N_NODES);
    hipLaunchKernelGGL(k_prep, dim3(20), dim3(256), 0, stream, W_src, W_dst, Wg1, fragT);
    hipLaunchKernelGGL(k_node_linear, dim3(782, 2), dim3(256), 0, stream,
                       x_src, x_dst, fragT, fragT + 16384, b_dst, ysrc, z);
    hipLaunchKernelGGL(k_gate, dim3(7813), dim3(256), 0, stream,
                       ea, fragT + 32768, bg1, Wg2, bg2, gate_h);
    hipLaunchKernelGGL(k_deg, dim3(3907), dim3(256), 0, stream, dstIdx, deg);
    hipLaunchKernelGGL(k_scan1, dim3(NSB), dim3(256), 0, stream, deg, bsum);
    hipLaunchKernelGGL(k_scan2, dim3(1), dim3(512), 0, stream, bsum, boff);
    hipLaunchKernelGGL(k_scan3, dim3(NSB), dim3(256), 0, stream, deg, boff, cursor);
    hipLaunchKernelGGL(k_fill, dim3(3907), dim3(256), 0, stream,
                       dstIdx, srcIdx, (const unsigned short*)gate_h, cursor, sg_s, sg_g);
    hipLaunchKernelGGL(k_agg, dim3(N_NODES / 4), dim3(256), 0, stream,
                       cursor, deg, sg_s, (const __half*)sg_g, ysrc, z, gamma, beta, out);
}

// Round 5
// 293.527 us; speedup vs baseline: 2.3359x; 1.0515x over previous
//
#include <hip/hip_runtime.h>
#include <hip/hip_fp16.h>
#include <math.h>

#define N_NODES 100000
#define N_EDGES 1000000
#define D_MODEL 128
#define EDGE_DIM 64
#define SCHUNK 250
#define NSB 400

typedef short bf16x8 __attribute__((ext_vector_type(8)));
typedef float f32x4 __attribute__((ext_vector_type(4)));

__device__ __forceinline__ short f2bf(float f) {
    union { float f; unsigned u; } v; v.f = f;
    unsigned r = v.u + 0x7FFFu + ((v.u >> 16) & 1u);
    return (short)(r >> 16);
}
// tanh-form GELU: x*sigmoid(2t), t = 0.79788456(x + 0.044715 x^3). Max abs dev ~4e-4.
__device__ __forceinline__ float gelu_fast(float x) {
    float t = 0.7978845608028654f * x * (1.0f + 0.044715f * x * x);
    float e = __expf(2.0f * t);
    return x * (1.0f - __builtin_amdgcn_rcpf(e + 1.0f));
}
__device__ __forceinline__ float sigmoid_fast(float x) {
    return __builtin_amdgcn_rcpf(1.0f + __expf(-x));
}
__device__ __forceinline__ float bflo(unsigned v) { return __uint_as_float(v << 16); }
__device__ __forceinline__ float bfhi(unsigned v) { return __uint_as_float(v & 0xFFFF0000u); }

// ---------------- zero deg
__global__ __launch_bounds__(256) void k_zero_int(int* __restrict__ p, int n) {
    int i = blockIdx.x * 256 + threadIdx.x;
    if (i < n) p[i] = 0;
}

// ---------------- one-shot: build bf16 B-fragment tables for W_src, W_dst, Wg1
// frag layout: [kb][nt][lane][e] ; value = W[kb*32 + (lane>>4)*8 + e][nt*16 + (lane&15)]
__global__ __launch_bounds__(256) void k_prep(
    const float* __restrict__ Ws, const float* __restrict__ Wd,
    const float* __restrict__ Wg1, short* __restrict__ frag)
{
    int g = blockIdx.x * 256 + threadIdx.x;
    if (g >= 5120) return;
    const float* W; short* T; int q;
    if (g < 2048)      { W = Ws;  T = frag;         q = g; }
    else if (g < 4096) { W = Wd;  T = frag + 16384; q = g - 2048; }
    else               { W = Wg1; T = frag + 32768; q = g - 4096; }
    int ls = q & 63, nt = (q >> 6) & 7, kb = q >> 9;
    int col = nt * 16 + (ls & 15);
    int k0 = kb * 32 + (ls >> 4) * 8;
    bf16x8 v;
    #pragma unroll
    for (int e = 0; e < 8; ++e) v[e] = f2bf(W[(k0 + e) * D_MODEL + col]);
    *reinterpret_cast<bf16x8*>(T + (size_t)q * 8) = v;
}

// ---------------- y_src = x_src@W_src (bf16), z_bf = bf16(x_dst@W_dst + b_dst)
__global__ __launch_bounds__(256, 2) void k_node_linear(
    const float* __restrict__ x_src, const float* __restrict__ x_dst,
    const short* __restrict__ WsrcF, const short* __restrict__ WdstF,
    const float* __restrict__ b_dst,
    short* __restrict__ ysrc, short* __restrict__ z_bf)
{
    __shared__ __align__(16) short Bf[4][8][64][8];  // 32 KB
    const int tid = threadIdx.x;
    const int lane = tid & 63;
    const int wid = tid >> 6;
    const int l15 = lane & 15;
    const int lg = lane >> 4;
    const int mat = blockIdx.y;
    const float* __restrict__ X = mat ? x_dst : x_src;
    const short* __restrict__ WF = mat ? WdstF : WsrcF;
    const int row0 = blockIdx.x * 128 + wid * 32;

    // issue A loads early
    float4 av[4][2][2];
    #pragma unroll
    for (int kb = 0; kb < 4; ++kb)
        #pragma unroll
        for (int st = 0; st < 2; ++st) {
            int r = min(row0 + st * 16 + l15, N_NODES - 1);
            const float* p = X + (size_t)r * D_MODEL + kb * 32 + lg * 8;
            av[kb][st][0] = *reinterpret_cast<const float4*>(p);
            av[kb][st][1] = *reinterpret_cast<const float4*>(p + 4);
        }
    // stage fragment table (contiguous copy)
    #pragma unroll
    for (int i = 0; i < 8; ++i)
        reinterpret_cast<int4*>(Bf)[tid + i * 256] =
            reinterpret_cast<const int4*>(WF)[tid + i * 256];
    __syncthreads();

    bf16x8 a[4][2];
    #pragma unroll
    for (int kb = 0; kb < 4; ++kb)
        #pragma unroll
        for (int st = 0; st < 2; ++st) {
            float4 v0 = av[kb][st][0], v1 = av[kb][st][1];
            bf16x8 t;
            t[0] = f2bf(v0.x); t[1] = f2bf(v0.y); t[2] = f2bf(v0.z); t[3] = f2bf(v0.w);
            t[4] = f2bf(v1.x); t[5] = f2bf(v1.y); t[6] = f2bf(v1.z); t[7] = f2bf(v1.w);
            a[kb][st] = t;
        }

    f32x4 acc[2][8];
    #pragma unroll
    for (int st = 0; st < 2; ++st)
        #pragma unroll
        for (int nt = 0; nt < 8; ++nt) { f32x4 zz = {0.f,0.f,0.f,0.f}; acc[st][nt] = zz; }

    #pragma unroll
    for (int kb = 0; kb < 4; ++kb)
        #pragma unroll
        for (int nt = 0; nt < 8; ++nt) {
            bf16x8 b = *reinterpret_cast<const bf16x8*>(&Bf[kb][nt][lane][0]);
            acc[0][nt] = __builtin_amdgcn_mfma_f32_16x16x32_bf16(a[kb][0], b, acc[0][nt], 0, 0, 0);
            acc[1][nt] = __builtin_amdgcn_mfma_f32_16x16x32_bf16(a[kb][1], b, acc[1][nt], 0, 0, 0);
        }

    #pragma unroll
    for (int st = 0; st < 2; ++st) {
        int rowb = row0 + st * 16 + lg * 4;
        #pragma unroll
        for (int nt = 0; nt < 8; ++nt) {
            int col = nt * 16 + l15;
            float bias = mat ? b_dst[col] : 0.0f;
            #pragma unroll
            for (int r = 0; r < 4; ++r) {
                int row = rowb + r;
                if (row < N_NODES) {
                    float v = acc[st][nt][r];
                    if (mat) z_bf[(size_t)row * D_MODEL + col] = f2bf(v + bias);
                    else     ysrc[(size_t)row * D_MODEL + col] = f2bf(v);
                }
            }
        }
    }
}

// ---------------- gate MLP + fused CSR scatter:
// gate = sigmoid(gelu(ea@Wg1+bg1)@Wg2+bg2); p = atomicAdd(cursor[dst]); sg[p] = (src, gate)
__global__ __launch_bounds__(256, 4) void k_gate_fill(
    const float* __restrict__ ea, const short* __restrict__ Wg1F,
    const float* __restrict__ bg1, const float* __restrict__ Wg2,
    const float* __restrict__ bg2,
    const int* __restrict__ dstI, const int* __restrict__ srcI,
    int* __restrict__ cursor, int* __restrict__ sg_s,
    unsigned short* __restrict__ sg_g)
{
    __shared__ __align__(16) short Bf[2][8][64][8];  // 16 KB
    const int tid = threadIdx.x;
    const int lane = tid & 63;
    const int wid = tid >> 6;
    const int l15 = lane & 15;
    const int lg = lane >> 4;
    const int e0 = blockIdx.x * 128 + wid * 32;

    // issue A loads early
    float4 av[2][2][2];
    #pragma unroll
    for (int kb = 0; kb < 2; ++kb)
        #pragma unroll
        for (int st = 0; st < 2; ++st) {
            int r = min(e0 + st * 16 + l15, N_EDGES - 1);
            const float* p = ea + (size_t)r * EDGE_DIM + kb * 32 + lg * 8;
            av[kb][st][0] = *reinterpret_cast<const float4*>(p);
            av[kb][st][1] = *reinterpret_cast<const float4*>(p + 4);
        }
    // prefetch epilogue vectors
    float b1v[2][4], w2v[2][4];
    #pragma unroll
    for (int ntc = 0; ntc < 2; ++ntc)
        #pragma unroll
        for (int nt = 0; nt < 4; ++nt) {
            int col = (ntc * 4 + nt) * 16 + l15;
            b1v[ntc][nt] = bg1[col];
            w2v[ntc][nt] = Wg2[col];
        }
    // stage Wg1 fragment table
    #pragma unroll
    for (int i = 0; i < 4; ++i)
        reinterpret_cast<int4*>(Bf)[tid + i * 256] =
            reinterpret_cast<const int4*>(Wg1F)[tid + i * 256];
    __syncthreads();

    bf16x8 a[2][2];
    #pragma unroll
    for (int kb = 0; kb < 2; ++kb)
        #pragma unroll
        for (int st = 0; st < 2; ++st) {
            float4 v0 = av[kb][st][0], v1 = av[kb][st][1];
            bf16x8 t;
            t[0] = f2bf(v0.x); t[1] = f2bf(v0.y); t[2] = f2bf(v0.z); t[3] = f2bf(v0.w);
            t[4] = f2bf(v1.x); t[5] = f2bf(v1.y); t[6] = f2bf(v1.z); t[7] = f2bf(v1.w);
            a[kb][st] = t;
        }

    float part[2][4] = {{0.f,0.f,0.f,0.f},{0.f,0.f,0.f,0.f}};
    #pragma unroll
    for (int ntc = 0; ntc < 2; ++ntc) {
        f32x4 acc[2][4];
        #pragma unroll
        for (int st = 0; st < 2; ++st)
            #pragma unroll
            for (int nt = 0; nt < 4; ++nt) { f32x4 zz = {0.f,0.f,0.f,0.f}; acc[st][nt] = zz; }
        #pragma unroll
        for (int kb = 0; kb < 2; ++kb)
            #pragma unroll
            for (int nt = 0; nt < 4; ++nt) {
                bf16x8 b = *reinterpret_cast<const bf16x8*>(&Bf[kb][ntc * 4 + nt][lane][0]);
                acc[0][nt] = __builtin_amdgcn_mfma_f32_16x16x32_bf16(a[kb][0], b, acc[0][nt], 0, 0, 0);
                acc[1][nt] = __builtin_amdgcn_mfma_f32_16x16x32_bf16(a[kb][1], b, acc[1][nt], 0, 0, 0);
            }
        #pragma unroll
        for (int nt = 0; nt < 4; ++nt) {
            float b1 = b1v[ntc][nt], w2 = w2v[ntc][nt];
            #pragma unroll
            for (int st = 0; st < 2; ++st)
                #pragma unroll
                for (int r = 0; r < 4; ++r)
                    part[st][r] += gelu_fast(acc[st][nt][r] + b1) * w2;
        }
    }

    #pragma unroll
    for (int m = 1; m <= 8; m <<= 1)
        #pragma unroll
        for (int st = 0; st < 2; ++st)
            #pragma unroll
            for (int r = 0; r < 4; ++r)
                part[st][r] += __shfl_xor(part[st][r], m);

    // fused fill: 16 result-holding lanes scatter (src, gate) into CSR order
    if (l15 == 0) {
        float b2 = bg2[0];
        #pragma unroll
        for (int st = 0; st < 2; ++st)
            #pragma unroll
            for (int r = 0; r < 4; ++r) {
                int e = e0 + st * 16 + lg * 4 + r;
                if (e < N_EDGES) {
                    float gv = sigmoid_fast(part[st][r] + b2);
                    int d = dstI[e];
                    int s = srcI[e];
                    int p = atomicAdd(&cursor[d], 1);
                    __half h = __float2half(gv);
                    sg_s[p] = s;
                    sg_g[p] = *reinterpret_cast<unsigned short*>(&h);
                }
            }
    }
}

// ---------------- CSR build (deg + 3-stage scan)
__global__ void k_deg(const int* __restrict__ dst, int* __restrict__ deg) {
    int e = blockIdx.x * 256 + threadIdx.x;
    if (e < N_EDGES) atomicAdd(&deg[dst[e]], 1);
}
__global__ __launch_bounds__(256) void k_scan1(const int* __restrict__ deg, int* __restrict__ bsum) {
    __shared__ int s[256];
    int tid = threadIdx.x;
    int i = blockIdx.x * SCHUNK + tid;
    int v = (tid < SCHUNK && i < N_NODES) ? deg[i] : 0;
    s[tid] = v; __syncthreads();
    for (int off = 128; off > 0; off >>= 1) {
        if (tid < off) s[tid] += s[tid + off];
        __syncthreads();
    }
    if (tid == 0) bsum[blockIdx.x] = s[0];
}
__global__ __launch_bounds__(512) void k_scan2(const int* __restrict__ bsum, int* __restrict__ boff) {
    __shared__ int s[512];
    int tid = threadIdx.x;
    int v = (tid < NSB) ? bsum[tid] : 0;
    s[tid] = v; __syncthreads();
    for (int off = 1; off < 512; off <<= 1) {
        int t = (tid >= off) ? s[tid - off] : 0;
        __syncthreads();
        s[tid] += t;
        __syncthreads();
    }
    if (tid < NSB) boff[tid] = s[tid] - v;
}
__global__ __launch_bounds__(256) void k_scan3(const int* __restrict__ deg, const int* __restrict__ boff,
                                               int* __restrict__ cursor) {
    __shared__ int s[256];
    int tid = threadIdx.x;
    int i = blockIdx.x * SCHUNK + tid;
    int v = (tid < SCHUNK && i < N_NODES) ? deg[i] : 0;
    s[tid] = v; __syncthreads();
    for (int off = 1; off < 256; off <<= 1) {
        int t = (tid >= off) ? s[tid - off] : 0;
        __syncthreads();
        s[tid] += t;
        __syncthreads();
    }
    int excl = s[tid] - v;
    if (tid < SCHUNK && i < N_NODES) cursor[i] = boff[blockIdx.x] + excl;
}

// ---------------- per-node gather + mean + residual + LN + GELU (one wave per node)
__global__ __launch_bounds__(256) void k_agg(
    const int* __restrict__ cursorEnd, const int* __restrict__ deg,
    const int* __restrict__ sg_s, const __half* __restrict__ sg_g,
    const short* __restrict__ ysrc, const short* __restrict__ z_bf,
    const float* __restrict__ gamma, const float* __restrict__ beta,
    float* __restrict__ out)
{
    const int lane = threadIdx.x & 63;
    const int wid = threadIdx.x >> 6;
    const int n = blockIdx.x * 4 + wid;
    const int dg = deg[n];
    const int start = cursorEnd[n] - dg;
    const int c0 = lane * 2;

    float a0 = 0.f, a1 = 0.f;
    int t = 0;
    for (; t + 4 <= dg; t += 4) {
        int s0 = sg_s[start + t + 0];
        int s1 = sg_s[start + t + 1];
        int s2 = sg_s[start + t + 2];
        int s3 = sg_s[start + t + 3];
        float g0 = __half2float(sg_g[start + t + 0]);
        float g1 = __half2float(sg_g[start + t + 1]);
        float g2 = __half2float(sg_g[start + t + 2]);
        float g3 = __half2float(sg_g[start + t + 3]);
        unsigned p0 = *reinterpret_cast<const unsigned*>(&ysrc[(size_t)s0 * D_MODEL + c0]);
        unsigned p1 = *reinterpret_cast<const unsigned*>(&ysrc[(size_t)s1 * D_MODEL + c0]);
        unsigned p2 = *reinterpret_cast<const unsigned*>(&ysrc[(size_t)s2 * D_MODEL + c0]);
        unsigned p3 = *reinterpret_cast<const unsigned*>(&ysrc[(size_t)s3 * D_MODEL + c0]);
        a0 += g0 * bflo(p0) + g1 * bflo(p1) + g2 * bflo(p2) + g3 * bflo(p3);
        a1 += g0 * bfhi(p0) + g1 * bfhi(p1) + g2 * bfhi(p2) + g3 * bfhi(p3);
    }
    for (; t < dg; ++t) {
        int s0 = sg_s[start + t];
        float g0 = __half2float(sg_g[start + t]);
        unsigned p0 = *reinterpret_cast<const unsigned*>(&ysrc[(size_t)s0 * D_MODEL + c0]);
        a0 += g0 * bflo(p0);
        a1 += g0 * bfhi(p0);
    }

    float inv = 1.0f / fmaxf((float)dg, 1.0f);
    unsigned zv = *reinterpret_cast<const unsigned*>(&z_bf[(size_t)n * D_MODEL + c0]);
    float t0 = a0 * inv + bflo(zv);
    float t1 = a1 * inv + bfhi(zv);

    float sum = t0 + t1;
    #pragma unroll
    for (int m = 1; m <= 32; m <<= 1) sum += __shfl_xor(sum, m);
    float mu = sum * (1.0f / 128.0f);
    float d0 = t0 - mu, d1 = t1 - mu;
    float vs = d0 * d0 + d1 * d1;
    #pragma unroll
    for (int m = 1; m <= 32; m <<= 1) vs += __shfl_xor(vs, m);
    float rstd = rsqrtf(vs * (1.0f / 128.0f) + 1e-5f);

    float2 gv = *reinterpret_cast<const float2*>(&gamma[c0]);
    float2 bv = *reinterpret_cast<const float2*>(&beta[c0]);
    float o0 = d0 * rstd * gv.x + bv.x;
    float o1 = d1 * rstd * gv.y + bv.y;
    float2 o = make_float2(gelu_fast(o0), gelu_fast(o1));
    *reinterpret_cast<float2*>(&out[(size_t)n * D_MODEL + c0]) = o;
}

extern "C" void kernel_launch(void* const* d_in, const int* in_sizes, int n_in,
                              void* d_out, int out_size, void* d_ws, size_t ws_size,
                              hipStream_t stream)
{
    const float* x_src = (const float*)d_in[0];
    const float* x_dst = (const float*)d_in[1];
    const float* ea    = (const float*)d_in[2];
    const int*   ei    = (const int*)d_in[3];
    const float* W_src = (const float*)d_in[4];
    const float* W_dst = (const float*)d_in[5];
    const float* b_dst = (const float*)d_in[6];
    const float* Wg1   = (const float*)d_in[7];
    const float* bg1   = (const float*)d_in[8];
    const float* Wg2   = (const float*)d_in[9];
    const float* bg2   = (const float*)d_in[10];
    const float* gamma = (const float*)d_in[11];
    const float* beta  = (const float*)d_in[12];
    const int* srcIdx = ei;
    const int* dstIdx = ei + N_EDGES;

    char* ws = (char*)d_ws;
    short*  fragT  = (short*)(ws);                   // 81,920 B (WsrcF | WdstF | Wg1F)
    short*  ysrc   = (short*)(ws + 81920);           // 25,600,000 B
    short*  z_bf   = (short*)(ws + 25681920);        // 25,600,000 B
    int*    deg    = (int*)(ws + 51281920);          //    400,000 B
    int*    cursor = (int*)(ws + 51681920);          //    400,000 B
    int*    sg_s   = (int*)(ws + 52081920);          //  4,000,000 B
    unsigned short* sg_g = (unsigned short*)(ws + 56081920); // 2,000,000 B
    int*    bsum   = (int*)(ws + 58081920);          //      1,600 B
    int*    boff   = (int*)(ws + 58083520);          //      1,600 B

    float* out = (float*)d_out;

    // CSR skeleton first so the gate kernel can scatter directly
    hipLaunchKernelGGL(k_zero_int, dim3((N_NODES + 255) / 256), dim3(256), 0, stream, deg, N_NODES);
    hipLaunchKernelGGL(k_deg, dim3(3907), dim3(256), 0, stream, dstIdx, deg);
    hipLaunchKernelGGL(k_scan1, dim3(NSB), dim3(256), 0, stream, deg, bsum);
    hipLaunchKernelGGL(k_scan2, dim3(1), dim3(512), 0, stream, bsum, boff);
    hipLaunchKernelGGL(k_scan3, dim3(NSB), dim3(256), 0, stream, deg, boff, cursor);
    hipLaunchKernelGGL(k_prep, dim3(20), dim3(256), 0, stream, W_src, W_dst, Wg1, fragT);
    hipLaunchKernelGGL(k_node_linear, dim3(782, 2), dim3(256), 0, stream,
                       x_src, x_dst, fragT, fragT + 16384, b_dst, ysrc, z_bf);
    hipLaunchKernelGGL(k_gate_fill, dim3(7813), dim3(256), 0, stream,
                       ea, fragT + 32768, bg1, Wg2, bg2, dstIdx, srcIdx, cursor, sg_s, sg_g);
    hipLaunchKernelGGL(k_agg, dim3(N_NODES / 4), dim3(256), 0, stream,
                       cursor, deg, sg_s, (const __half*)sg_g, ysrc, z_bf, gamma, beta, out);
}

// Round 6
// 277.818 us; speedup vs baseline: 2.4679x; 1.0565x over previous
//
#include <hip/hip_runtime.h>
#include <hip/hip_fp16.h>
#include <math.h>

#define N_NODES 100000
#define N_EDGES 1000000
#define D_MODEL 128
#define EDGE_DIM 64
#define SCHUNK 250
#define NSB 400

typedef short bf16x8 __attribute__((ext_vector_type(8)));
typedef float f32x4 __attribute__((ext_vector_type(4)));

__device__ __forceinline__ short f2bf(float f) {
    union { float f; unsigned u; } v; v.f = f;
    unsigned r = v.u + 0x7FFFu + ((v.u >> 16) & 1u);
    return (short)(r >> 16);
}
// tanh-form GELU: max abs dev ~4e-4
__device__ __forceinline__ float gelu_fast(float x) {
    float t = 0.7978845608028654f * x * (1.0f + 0.044715f * x * x);
    float e = __expf(2.0f * t);
    return x * (1.0f - __builtin_amdgcn_rcpf(e + 1.0f));
}
__device__ __forceinline__ float sigmoid_fast(float x) {
    return __builtin_amdgcn_rcpf(1.0f + __expf(-x));
}
__device__ __forceinline__ float bflo(unsigned v) { return __uint_as_float(v << 16); }
__device__ __forceinline__ float bfhi(unsigned v) { return __uint_as_float(v & 0xFFFF0000u); }

// ---------------- one-shot: bf16 B-fragment tables for W_src, W_dst, Wg1 + zero deg
// frag layout: [kb][nt][lane][e] ; value = W[kb*32 + (lane>>4)*8 + e][nt*16 + (lane&15)]
__global__ __launch_bounds__(256) void k_prep(
    const float* __restrict__ Ws, const float* __restrict__ Wd,
    const float* __restrict__ Wg1, short* __restrict__ frag,
    int* __restrict__ deg)
{
    int b = blockIdx.x;
    if (b >= 20) {  // zero-deg portion
        int i = (b - 20) * 256 + threadIdx.x;
        if (i < N_NODES) deg[i] = 0;
        return;
    }
    int g = b * 256 + threadIdx.x;
    if (g >= 5120) return;
    const float* W; short* T; int q;
    if (g < 2048)      { W = Ws;  T = frag;         q = g; }
    else if (g < 4096) { W = Wd;  T = frag + 16384; q = g - 2048; }
    else               { W = Wg1; T = frag + 32768; q = g - 4096; }
    int ls = q & 63, nt = (q >> 6) & 7, kb = q >> 9;
    int col = nt * 16 + (ls & 15);
    int k0 = kb * 32 + (ls >> 4) * 8;
    bf16x8 v;
    #pragma unroll
    for (int e = 0; e < 8; ++e) v[e] = f2bf(W[(k0 + e) * D_MODEL + col]);
    *reinterpret_cast<bf16x8*>(T + (size_t)q * 8) = v;
}

// ---------------- degree count; atomic return value = rank of edge within its dst
__global__ void k_deg(const int* __restrict__ dst, int* __restrict__ deg, int* __restrict__ rank) {
    int e = blockIdx.x * 256 + threadIdx.x;
    if (e < N_EDGES) rank[e] = atomicAdd(&deg[dst[e]], 1);
}

// ---------------- 3-stage exclusive scan -> rstart (with rstart[N]=E sentinel)
__global__ __launch_bounds__(256) void k_scan1(const int* __restrict__ deg, int* __restrict__ bsum) {
    __shared__ int s[256];
    int tid = threadIdx.x;
    int i = blockIdx.x * SCHUNK + tid;
    int v = (tid < SCHUNK && i < N_NODES) ? deg[i] : 0;
    s[tid] = v; __syncthreads();
    for (int off = 128; off > 0; off >>= 1) {
        if (tid < off) s[tid] += s[tid + off];
        __syncthreads();
    }
    if (tid == 0) bsum[blockIdx.x] = s[0];
}
__global__ __launch_bounds__(512) void k_scan2(const int* __restrict__ bsum, int* __restrict__ boff) {
    __shared__ int s[512];
    int tid = threadIdx.x;
    int v = (tid < NSB) ? bsum[tid] : 0;
    s[tid] = v; __syncthreads();
    for (int off = 1; off < 512; off <<= 1) {
        int t = (tid >= off) ? s[tid - off] : 0;
        __syncthreads();
        s[tid] += t;
        __syncthreads();
    }
    if (tid < NSB) boff[tid] = s[tid] - v;
}
__global__ __launch_bounds__(256) void k_scan3(const int* __restrict__ deg, const int* __restrict__ boff,
                                               int* __restrict__ rstart) {
    __shared__ int s[256];
    int tid = threadIdx.x;
    int i = blockIdx.x * SCHUNK + tid;
    int v = (tid < SCHUNK && i < N_NODES) ? deg[i] : 0;
    s[tid] = v; __syncthreads();
    for (int off = 1; off < 256; off <<= 1) {
        int t = (tid >= off) ? s[tid - off] : 0;
        __syncthreads();
        s[tid] += t;
        __syncthreads();
    }
    int excl = s[tid] - v;
    if (tid < SCHUNK && i < N_NODES) {
        rstart[i] = boff[blockIdx.x] + excl;
        if (i == N_NODES - 1) rstart[N_NODES] = boff[blockIdx.x] + excl + v;  // = N_EDGES
    }
}

// ---------------- y_src = x_src@W_src (bf16), z_bf = bf16(x_dst@W_dst + b_dst)
// kb-pipelined A loads (double-buffered, fully unrolled -> static indexing)
__global__ __launch_bounds__(256, 3) void k_node_linear(
    const float* __restrict__ x_src, const float* __restrict__ x_dst,
    const short* __restrict__ WsrcF, const short* __restrict__ WdstF,
    const float* __restrict__ b_dst,
    short* __restrict__ ysrc, short* __restrict__ z_bf)
{
    __shared__ __align__(16) short Bf[4][8][64][8];  // 32 KB
    const int tid = threadIdx.x;
    const int lane = tid & 63;
    const int wid = tid >> 6;
    const int l15 = lane & 15;
    const int lg = lane >> 4;
    const int mat = blockIdx.y;
    const float* __restrict__ X = mat ? x_dst : x_src;
    const short* __restrict__ WF = mat ? WdstF : WsrcF;
    const int row0 = blockIdx.x * 128 + wid * 32;

    const float* rowp[2];
    #pragma unroll
    for (int st = 0; st < 2; ++st) {
        int r = min(row0 + st * 16 + l15, N_NODES - 1);
        rowp[st] = X + (size_t)r * D_MODEL + lg * 8;
    }

    float4 buf[2][2][2];
    #pragma unroll
    for (int st = 0; st < 2; ++st) {
        buf[0][st][0] = *reinterpret_cast<const float4*>(rowp[st]);
        buf[0][st][1] = *reinterpret_cast<const float4*>(rowp[st] + 4);
    }

    // stage fragment table (contiguous copy)
    #pragma unroll
    for (int i = 0; i < 8; ++i)
        reinterpret_cast<int4*>(Bf)[tid + i * 256] =
            reinterpret_cast<const int4*>(WF)[tid + i * 256];

    f32x4 acc[2][8];
    #pragma unroll
    for (int st = 0; st < 2; ++st)
        #pragma unroll
        for (int nt = 0; nt < 8; ++nt) { f32x4 zz = {0.f,0.f,0.f,0.f}; acc[st][nt] = zz; }

    __syncthreads();

    #pragma unroll
    for (int kb = 0; kb < 4; ++kb) {
        if (kb < 3) {
            #pragma unroll
            for (int st = 0; st < 2; ++st) {
                buf[(kb + 1) & 1][st][0] = *reinterpret_cast<const float4*>(rowp[st] + (kb + 1) * 32);
                buf[(kb + 1) & 1][st][1] = *reinterpret_cast<const float4*>(rowp[st] + (kb + 1) * 32 + 4);
            }
        }
        bf16x8 a[2];
        #pragma unroll
        for (int st = 0; st < 2; ++st) {
            float4 v0 = buf[kb & 1][st][0], v1 = buf[kb & 1][st][1];
            bf16x8 t;
            t[0] = f2bf(v0.x); t[1] = f2bf(v0.y); t[2] = f2bf(v0.z); t[3] = f2bf(v0.w);
            t[4] = f2bf(v1.x); t[5] = f2bf(v1.y); t[6] = f2bf(v1.z); t[7] = f2bf(v1.w);
            a[st] = t;
        }
        #pragma unroll
        for (int nt = 0; nt < 8; ++nt) {
            bf16x8 b = *reinterpret_cast<const bf16x8*>(&Bf[kb][nt][lane][0]);
            acc[0][nt] = __builtin_amdgcn_mfma_f32_16x16x32_bf16(a[0], b, acc[0][nt], 0, 0, 0);
            acc[1][nt] = __builtin_amdgcn_mfma_f32_16x16x32_bf16(a[1], b, acc[1][nt], 0, 0, 0);
        }
    }

    #pragma unroll
    for (int st = 0; st < 2; ++st) {
        int rowb = row0 + st * 16 + lg * 4;
        #pragma unroll
        for (int nt = 0; nt < 8; ++nt) {
            int col = nt * 16 + l15;
            float bias = mat ? b_dst[col] : 0.0f;
            #pragma unroll
            for (int r = 0; r < 4; ++r) {
                int row = rowb + r;
                if (row < N_NODES) {
                    float v = acc[st][nt][r];
                    if (mat) z_bf[(size_t)row * D_MODEL + col] = f2bf(v + bias);
                    else     ysrc[(size_t)row * D_MODEL + col] = f2bf(v);
                }
            }
        }
    }
}

// ---------------- gate MLP + atomic-free CSR scatter via precomputed rank:
// gate = sigmoid(gelu(ea@Wg1+bg1)@Wg2+bg2); p = rstart[dst[e]] + rank[e]; sg[p] = {src, gate}
__global__ __launch_bounds__(256, 4) void k_gate_fill(
    const float* __restrict__ ea, const short* __restrict__ Wg1F,
    const float* __restrict__ bg1, const float* __restrict__ Wg2,
    const float* __restrict__ bg2,
    const int* __restrict__ dstI, const int* __restrict__ srcI,
    const int* __restrict__ rank, const int* __restrict__ rstart,
    int2* __restrict__ sg)
{
    __shared__ __align__(16) short Bf[2][8][64][8];  // 16 KB
    const int tid = threadIdx.x;
    const int lane = tid & 63;
    const int wid = tid >> 6;
    const int l15 = lane & 15;
    const int lg = lane >> 4;
    const int e0 = blockIdx.x * 128 + wid * 32;

    // issue A loads early
    float4 av[2][2][2];
    #pragma unroll
    for (int kb = 0; kb < 2; ++kb)
        #pragma unroll
        for (int st = 0; st < 2; ++st) {
            int r = min(e0 + st * 16 + l15, N_EDGES - 1);
            const float* p = ea + (size_t)r * EDGE_DIM + kb * 32 + lg * 8;
            av[kb][st][0] = *reinterpret_cast<const float4*>(p);
            av[kb][st][1] = *reinterpret_cast<const float4*>(p + 4);
        }
    // stage Wg1 fragment table
    #pragma unroll
    for (int i = 0; i < 4; ++i)
        reinterpret_cast<int4*>(Bf)[tid + i * 256] =
            reinterpret_cast<const int4*>(Wg1F)[tid + i * 256];
    __syncthreads();

    bf16x8 a[2][2];
    #pragma unroll
    for (int kb = 0; kb < 2; ++kb)
        #pragma unroll
        for (int st = 0; st < 2; ++st) {
            float4 v0 = av[kb][st][0], v1 = av[kb][st][1];
            bf16x8 t;
            t[0] = f2bf(v0.x); t[1] = f2bf(v0.y); t[2] = f2bf(v0.z); t[3] = f2bf(v0.w);
            t[4] = f2bf(v1.x); t[5] = f2bf(v1.y); t[6] = f2bf(v1.z); t[7] = f2bf(v1.w);
            a[kb][st] = t;
        }

    float part[2][4] = {{0.f,0.f,0.f,0.f},{0.f,0.f,0.f,0.f}};
    #pragma unroll
    for (int ntc = 0; ntc < 2; ++ntc) {
        f32x4 acc[2][4];
        #pragma unroll
        for (int st = 0; st < 2; ++st)
            #pragma unroll
            for (int nt = 0; nt < 4; ++nt) { f32x4 zz = {0.f,0.f,0.f,0.f}; acc[st][nt] = zz; }
        #pragma unroll
        for (int kb = 0; kb < 2; ++kb)
            #pragma unroll
            for (int nt = 0; nt < 4; ++nt) {
                bf16x8 b = *reinterpret_cast<const bf16x8*>(&Bf[kb][ntc * 4 + nt][lane][0]);
                acc[0][nt] = __builtin_amdgcn_mfma_f32_16x16x32_bf16(a[kb][0], b, acc[0][nt], 0, 0, 0);
                acc[1][nt] = __builtin_amdgcn_mfma_f32_16x16x32_bf16(a[kb][1], b, acc[1][nt], 0, 0, 0);
            }
        #pragma unroll
        for (int nt = 0; nt < 4; ++nt) {
            int col = (ntc * 4 + nt) * 16 + l15;
            float b1 = bg1[col];
            float w2 = Wg2[col];
            #pragma unroll
            for (int st = 0; st < 2; ++st)
                #pragma unroll
                for (int r = 0; r < 4; ++r)
                    part[st][r] += gelu_fast(acc[st][nt][r] + b1) * w2;
        }
    }

    #pragma unroll
    for (int m = 1; m <= 8; m <<= 1)
        #pragma unroll
        for (int st = 0; st < 2; ++st)
            #pragma unroll
            for (int r = 0; r < 4; ++r)
                part[st][r] += __shfl_xor(part[st][r], m);

    // atomic-free scatter: 16 result-holding lanes place (src, gate) into CSR slot
    if (l15 == 0) {
        float b2 = bg2[0];
        #pragma unroll
        for (int st = 0; st < 2; ++st)
            #pragma unroll
            for (int r = 0; r < 4; ++r) {
                int e = e0 + st * 16 + lg * 4 + r;
                if (e < N_EDGES) {
                    float gv = sigmoid_fast(part[st][r] + b2);
                    int d = dstI[e];
                    int p = rstart[d] + rank[e];
                    int2 v; v.x = srcI[e]; v.y = __float_as_int(gv);
                    sg[p] = v;
                }
            }
    }
}

// ---------------- per-node gather + mean + residual + LN + GELU (one wave per node)
__global__ __launch_bounds__(256) void k_agg(
    const int* __restrict__ rstart, const int2* __restrict__ sg,
    const short* __restrict__ ysrc, const short* __restrict__ z_bf,
    const float* __restrict__ gamma, const float* __restrict__ beta,
    float* __restrict__ out)
{
    const int lane = threadIdx.x & 63;
    const int wid = threadIdx.x >> 6;
    const int n = blockIdx.x * 4 + wid;
    const int start = rstart[n];
    const int end = rstart[n + 1];
    const int dg = end - start;
    const int c0 = lane * 2;

    // node-constant loads issued early
    unsigned zv = *reinterpret_cast<const unsigned*>(&z_bf[(size_t)n * D_MODEL + c0]);
    float2 gv = *reinterpret_cast<const float2*>(&gamma[c0]);
    float2 bv = *reinterpret_cast<const float2*>(&beta[c0]);

    float a0 = 0.f, a1 = 0.f;
    int t = start;
    for (; t + 4 <= end; t += 4) {
        int2 e0 = sg[t + 0];
        int2 e1 = sg[t + 1];
        int2 e2 = sg[t + 2];
        int2 e3 = sg[t + 3];
        unsigned p0 = *reinterpret_cast<const unsigned*>(&ysrc[(size_t)e0.x * D_MODEL + c0]);
        unsigned p1 = *reinterpret_cast<const unsigned*>(&ysrc[(size_t)e1.x * D_MODEL + c0]);
        unsigned p2 = *reinterpret_cast<const unsigned*>(&ysrc[(size_t)e2.x * D_MODEL + c0]);
        unsigned p3 = *reinterpret_cast<const unsigned*>(&ysrc[(size_t)e3.x * D_MODEL + c0]);
        float g0 = __int_as_float(e0.y), g1 = __int_as_float(e1.y);
        float g2 = __int_as_float(e2.y), g3 = __int_as_float(e3.y);
        a0 += g0 * bflo(p0) + g1 * bflo(p1) + g2 * bflo(p2) + g3 * bflo(p3);
        a1 += g0 * bfhi(p0) + g1 * bfhi(p1) + g2 * bfhi(p2) + g3 * bfhi(p3);
    }
    for (; t < end; ++t) {
        int2 e0 = sg[t];
        float g0 = __int_as_float(e0.y);
        unsigned p0 = *reinterpret_cast<const unsigned*>(&ysrc[(size_t)e0.x * D_MODEL + c0]);
        a0 += g0 * bflo(p0);
        a1 += g0 * bfhi(p0);
    }

    float inv = 1.0f / fmaxf((float)dg, 1.0f);
    float t0 = a0 * inv + bflo(zv);
    float t1 = a1 * inv + bfhi(zv);

    float sum = t0 + t1;
    #pragma unroll
    for (int m = 1; m <= 32; m <<= 1) sum += __shfl_xor(sum, m);
    float mu = sum * (1.0f / 128.0f);
    float d0 = t0 - mu, d1 = t1 - mu;
    float vs = d0 * d0 + d1 * d1;
    #pragma unroll
    for (int m = 1; m <= 32; m <<= 1) vs += __shfl_xor(vs, m);
    float rstd = rsqrtf(vs * (1.0f / 128.0f) + 1e-5f);

    float o0 = d0 * rstd * gv.x + bv.x;
    float o1 = d1 * rstd * gv.y + bv.y;
    float2 o = make_float2(gelu_fast(o0), gelu_fast(o1));
    *reinterpret_cast<float2*>(&out[(size_t)n * D_MODEL + c0]) = o;
}

extern "C" void kernel_launch(void* const* d_in, const int* in_sizes, int n_in,
                              void* d_out, int out_size, void* d_ws, size_t ws_size,
                              hipStream_t stream)
{
    const float* x_src = (const float*)d_in[0];
    const float* x_dst = (const float*)d_in[1];
    const float* ea    = (const float*)d_in[2];
    const int*   ei    = (const int*)d_in[3];
    const float* W_src = (const float*)d_in[4];
    const float* W_dst = (const float*)d_in[5];
    const float* b_dst = (const float*)d_in[6];
    const float* Wg1   = (const float*)d_in[7];
    const float* bg1   = (const float*)d_in[8];
    const float* Wg2   = (const float*)d_in[9];
    const float* bg2   = (const float*)d_in[10];
    const float* gamma = (const float*)d_in[11];
    const float* beta  = (const float*)d_in[12];
    const int* srcIdx = ei;
    const int* dstIdx = ei + N_EDGES;

    char* ws = (char*)d_ws;
    short* fragT  = (short*)(ws);                  // 81,920 B
    short* ysrc   = (short*)(ws + 81920);          // 25,600,000 B
    short* z_bf   = (short*)(ws + 25681920);       // 25,600,000 B
    int*   deg    = (int*)(ws + 51281920);         //    400,000 B
    int*   rank   = (int*)(ws + 51681920);         //  4,000,000 B
    int*   rstart = (int*)(ws + 55681920);         //    400,004 B
    int2*  sg     = (int2*)(ws + 56082336);        //  8,000,000 B
    int*   bsum   = (int*)(ws + 64082336);         //      1,600 B
    int*   boff   = (int*)(ws + 64084000);         //      1,600 B

    float* out = (float*)d_out;

    hipLaunchKernelGGL(k_prep, dim3(411), dim3(256), 0, stream, W_src, W_dst, Wg1, fragT, deg);
    hipLaunchKernelGGL(k_deg, dim3(3907), dim3(256), 0, stream, dstIdx, deg, rank);
    hipLaunchKernelGGL(k_scan1, dim3(NSB), dim3(256), 0, stream, deg, bsum);
    hipLaunchKernelGGL(k_scan2, dim3(1), dim3(512), 0, stream, bsum, boff);
    hipLaunchKernelGGL(k_scan3, dim3(NSB), dim3(256), 0, stream, deg, boff, rstart);
    hipLaunchKernelGGL(k_node_linear, dim3(782, 2), dim3(256), 0, stream,
                       x_src, x_dst, fragT, fragT + 16384, b_dst, ysrc, z_bf);
    hipLaunchKernelGGL(k_gate_fill, dim3(7813), dim3(256), 0, stream,
                       ea, fragT + 32768, bg1, Wg2, bg2, dstIdx, srcIdx, rank, rstart, sg);
    hipLaunchKernelGGL(k_agg, dim3(N_NODES / 4), dim3(256), 0, stream,
                       rstart, sg, ysrc, z_bf, gamma, beta, out);
}